// Round 16
// baseline (439.673 us; speedup 1.0000x reference)
//
#include <hip/hip_runtime.h>

#define T_  4
#define BN_ 8192
#define D_  512
#define H_  2048

typedef float f4 __attribute__((ext_vector_type(4)));
typedef float f32x4 __attribute__((ext_vector_type(4)));
typedef _Float16 f16x8 __attribute__((ext_vector_type(8)));

// hi = RN_f16(v), lo = RN_f16(v - hi); v - (float)hi is exact (Sterbenz).
__device__ __forceinline__ void split8(const f4 u0, const f4 u1, f16x8& hi, f16x8& lo) {
#pragma unroll
    for (int i = 0; i < 4; ++i) {
        _Float16 a = (_Float16)u0[i]; hi[i]     = a; lo[i]     = (_Float16)(u0[i] - (float)a);
        _Float16 b = (_Float16)u1[i]; hi[4 + i] = b; lo[4 + i] = (_Float16)(u1[i] - (float)b);
    }
}

// 4 spike bytes (0/1) -> 4 packed f16 in two u32 (exact).
__device__ __forceinline__ void spikes4_to_f16(unsigned b, unsigned& lo, unsigned& hi) {
    const unsigned p0 = (b & 0xFFu) | ((b & 0xFF00u) << 8);
    const unsigned p1 = ((b >> 16) & 0xFFu) | ((b >> 8) & 0xFF0000u);
    lo = p0 * 0x3C00u;
    hi = p1 * 0x3C00u;
}

// ---------------------------------------------------------------------------
// k_split: x fp32 [t][bn][k] -> xs (d_out scratch), 16KB chunk per (bnB32,kb):
// [t4][sp2][kg4][row32][k8] f16 (matches fc1's LDS image exactly).
// ---------------------------------------------------------------------------
__global__ __launch_bounds__(256)
void k_split(const float* __restrict__ x, _Float16* __restrict__ xs)
{
    const int b     = blockIdx.x;         // 8192 blocks
    const int t     = b & 3;
    const int k0B   = (b >> 2) & 15;
    const int bnB64 = b >> 6;
    const int kg    = threadIdx.x & 3;
    const int row64 = threadIdx.x >> 2;

    const float* src = x + ((size_t)t * BN_ + bnB64 * 64 + row64) * D_ + k0B * 32 + kg * 8;
    const f4 u0 = *(const f4*)src;
    const f4 u1 = *(const f4*)(src + 4);
    f16x8 hi, lo;
    split8(u0, u1, hi, lo);

    const int bnB32 = bnB64 * 2 + (row64 >> 5);
    const int r     = row64 & 31;
    const size_t base = (size_t)(bnB32 * 16 + k0B) * 8192 + t * 2048;
    *(f16x8*)&xs[base +        kg * 256 + r * 8] = hi;   // sp0
    *(f16x8*)&xs[base + 1024 + kg * 256 + r * 8] = lo;   // sp1
}

// ---------------------------------------------------------------------------
// k_splitW: W1 fp32 [h][k] -> w1s f16 fragment image:
// per (h0b,kb) a 16KB chunk = [sp2][kg4][col128][k8].
// ---------------------------------------------------------------------------
__global__ __launch_bounds__(256)
void k_splitW(const float* __restrict__ W1, _Float16* __restrict__ w1s)
{
    const int gid = blockIdx.x * 256 + threadIdx.x;   // 131072 total
    const int col = gid & 127;
    const int kg  = (gid >> 7) & 3;
    const int kb  = (gid >> 9) & 15;
    const int h0b = gid >> 13;                         // 0..15

    const float* src = W1 + (size_t)(h0b * 128 + col) * D_ + kb * 32 + kg * 8;
    const f4 u0 = *(const f4*)src;
    const f4 u1 = *(const f4*)(src + 4);
    f16x8 hi, lo;
    split8(u0, u1, hi, lo);

    const size_t base = (size_t)(h0b * 16 + kb) * 8192;
    *(f16x8*)&w1s[base +        kg * 1024 + col * 8] = hi;   // sp0
    *(f16x8*)&w1s[base + 4096 + kg * 1024 + col * 8] = lo;   // sp1
}

// ---------------------------------------------------------------------------
// k_splitW2: W2 fp32 [d][h] -> w2s f16 fragment image:
// per (d0b 0..3, kb 0..63) a 16KB chunk = [sp2][kg4][col128][k8].
// ---------------------------------------------------------------------------
__global__ __launch_bounds__(256)
void k_splitW2(const float* __restrict__ W2, _Float16* __restrict__ w2s)
{
    const int gid = blockIdx.x * 256 + threadIdx.x;   // 131072 total
    const int col = gid & 127;
    const int kg  = (gid >> 7) & 3;
    const int kb  = (gid >> 9) & 63;
    const int d0b = gid >> 15;                         // 0..3

    const float* src = W2 + (size_t)(d0b * 128 + col) * H_ + kb * 32 + kg * 8;
    const f4 u0 = *(const f4*)src;
    const f4 u1 = *(const f4*)(src + 4);
    f16x8 hi, lo;
    split8(u0, u1, hi, lo);

    const size_t base = (size_t)(d0b * 64 + kb) * 8192;
    *(f16x8*)&w2s[base +        kg * 1024 + col * 8] = hi;   // sp0
    *(f16x8*)&w2s[base + 4096 + kg * 1024 + col * 8] = lo;   // sp1
}

// ---------------------------------------------------------------------------
// fc1 (fc2b-clone structure): h = x @ W1^T, 3-product f16 split, all 4 t
// fused, 16x16x32 MFMA (16 indep acc chains/wave). A tile: pre-split xs ->
// REGS at phase top (latency hides under MFMA) -> write-late to LDS dbuf
// (2x16KB) -> __syncthreads. B: pre-split w1s -> ping-pong regs. T5 setprio.
// Tile 32(bn) x 128(h), 4 waves side-by-side. PLIF, u8 out.
// ---------------------------------------------------------------------------
__global__ __launch_bounds__(256, 2)
void k_fc1d(const _Float16* __restrict__ xs, const _Float16* __restrict__ w1s,
            const float* __restrict__ alphap, unsigned char* __restrict__ s1)
{
    __shared__ _Float16 Ab[2][T_][2][4][32][8];   // [buf][t][sp][kg][row][k8]  2x16KB

    const int tid  = threadIdx.x;
    const int lane = tid & 63;
    const int w    = tid >> 6;
    const int wc   = w * 32;                      // per-wave 32-col slice

    // panel swizzle: 16 panels of 256 blocks; within a panel the 16 readers of
    // one xs chunk (all h0i, fixed bnL) share gid%8 -> same XCD L2.
    const int gid   = blockIdx.x;                 // 0..4095
    const int panel = gid >> 8;
    const int h0i   = (gid >> 4) & 15;
    const int bnL   = gid & 15;
    const int bnB   = panel * 16 + bnL;           // 0..255
    const int bn0   = bnB * 32;
    const int h0    = h0i * 128;

    const int l15 = lane & 15;
    const int kgl = lane >> 4;
    const int lq  = kgl * 4;

    const float a1v = alphap[0];

    f32x4 acc[T_][2][2];
#pragma unroll
    for (int t = 0; t < T_; ++t)
#pragma unroll
        for (int m = 0; m < 2; ++m)
#pragma unroll
            for (int n = 0; n < 2; ++n) acc[t][m][n] = (f32x4){0.f, 0.f, 0.f, 0.f};

    const char* xbase = (const char*)xs + (size_t)bnB * 16 * 16384;
    const _Float16* bl = w1s + (size_t)h0i * (16 * 8192)
                             + (size_t)kgl * 1024 + (size_t)(wc + l15) * 8;

    // A stage: thread copies 64B of the 16KB tile (xs image == LDS image).
    _Float16* const aw = &Ab[0][0][0][0][0][0];   // base; buf offset added below

#define FC1_ALOAD(KB, R)                                                         \
    {                                                                            \
        const char* cb_ = xbase + (size_t)(KB) * 16384 + tid * 64;               \
        R[0] = *(const uint4*)(cb_);                                             \
        R[1] = *(const uint4*)(cb_ + 16);                                        \
        R[2] = *(const uint4*)(cb_ + 32);                                        \
        R[3] = *(const uint4*)(cb_ + 48);                                        \
    }

#define FC1_AWRITE(BUF, R)                                                       \
    {                                                                            \
        _Float16* lp_ = aw + (BUF) * 8192 + tid * 32;                            \
        *(uint4*)(lp_)      = R[0];                                              \
        *(uint4*)(lp_ + 8)  = R[1];                                              \
        *(uint4*)(lp_ + 16) = R[2];                                              \
        *(uint4*)(lp_ + 24) = R[3];                                              \
    }

#define FC1_BLOAD(KB, B0, B1)                                                    \
    {                                                                            \
        const _Float16* bp_ = bl + (size_t)(KB) * 8192;                          \
        B0[0] = *(const f16x8*)(bp_);                                            \
        B0[1] = *(const f16x8*)(bp_ + 128);                                      \
        B1[0] = *(const f16x8*)(bp_ + 4096);                                     \
        B1[1] = *(const f16x8*)(bp_ + 4096 + 128);                               \
    }

#define FC1_COMPUTE(BUF, B0, B1)                                                 \
    __builtin_amdgcn_s_setprio(1);                                               \
    _Pragma("unroll")                                                            \
    for (int t_ = 0; t_ < T_; ++t_)                                              \
        _Pragma("unroll")                                                        \
        for (int m_ = 0; m_ < 2; ++m_) {                                         \
            const f16x8 a0_ = *(const f16x8*)&Ab[BUF][t_][0][kgl][m_ * 16 + l15][0]; \
            const f16x8 a1_ = *(const f16x8*)&Ab[BUF][t_][1][kgl][m_ * 16 + l15][0]; \
            _Pragma("unroll")                                                    \
            for (int n_ = 0; n_ < 2; ++n_) {                                     \
                acc[t_][m_][n_] = __builtin_amdgcn_mfma_f32_16x16x32_f16(a0_, B0[n_], acc[t_][m_][n_], 0, 0, 0); \
                acc[t_][m_][n_] = __builtin_amdgcn_mfma_f32_16x16x32_f16(a0_, B1[n_], acc[t_][m_][n_], 0, 0, 0); \
                acc[t_][m_][n_] = __builtin_amdgcn_mfma_f32_16x16x32_f16(a1_, B0[n_], acc[t_][m_][n_], 0, 0, 0); \
            }                                                                    \
        }                                                                        \
    __builtin_amdgcn_s_setprio(0);

    f16x8 bc0[2], bc1[2], bp0[2], bp1[2];
    uint4 ar[4];

    // prologue: stage tile 0 (A -> regs -> LDS buf0; B -> current reg set)
    FC1_ALOAD(0, ar)
    FC1_BLOAD(0, bc0, bc1)
    FC1_AWRITE(0, ar)
    __syncthreads();

    int cur = 0;
#pragma unroll 1
    for (int kb = 0; kb < 16; ++kb) {
        if (kb < 15) {                 // prefetch next A (regs) + next B (regs)
            FC1_ALOAD(kb + 1, ar)
            FC1_BLOAD(kb + 1, bp0, bp1)
        }

        FC1_COMPUTE(cur, bc0, bc1)     // 48 MFMA/wave

        if (kb < 15) {                 // write-late A staging into other buffer
            FC1_AWRITE(cur ^ 1, ar)
        }
        __syncthreads();
        if (kb < 15) {
#pragma unroll
            for (int n = 0; n < 2; ++n) { bc0[n] = bp0[n]; bc1[n] = bp1[n]; }
        }
        cur ^= 1;
    }

    // ---- PLIF scan over t, write u8 spikes
#pragma unroll
    for (int m = 0; m < 2; ++m)
#pragma unroll
        for (int n = 0; n < 2; ++n)
#pragma unroll
            for (int q = 0; q < 4; ++q) {
                float v = 0.f;
#pragma unroll
                for (int t = 0; t < T_; ++t) {
                    v = v + a1v * (acc[t][m][n][q] - v);
                    const bool sp = (v >= 1.0f);
                    s1[((size_t)t * BN_ + bn0 + m * 16 + lq + q) * H_ +
                       (h0 + wc + n * 16 + l15)] = sp ? (unsigned char)1 : (unsigned char)0;
                    if (sp) v = 0.f;
                }
            }
}

// ---------------------------------------------------------------------------
// fc2b: y = s1 @ W2^T, all 4 t fused. A = binary spikes (exact f16) staged in
// LDS (dbuf 2x16KB); B = pre-split w2s loaded DIRECT to ping-pong registers.
// Tile 64(bn) x 128(d), 4 waves. T5 setprio around MFMA. PLIF, f32 out.
// ---------------------------------------------------------------------------
__global__ __launch_bounds__(256, 2)
void k_fc2b(const unsigned char* __restrict__ s1, const _Float16* __restrict__ w2s,
            const float* __restrict__ alphap, float* __restrict__ out)
{
    __shared__ _Float16 A2[2][T_][4][64][8];     // [buf][t][kg][row][k8]  32KB

    const int tid  = threadIdx.x;
    const int lane = tid & 63;
    const int w    = tid >> 6;
    const int wr   = (w >> 1) * 32;
    const int wc   = (w & 1) * 64;
    const int bn0  = blockIdx.x * 64;
    const int d0i  = blockIdx.y;
    const int d0   = d0i * 128;

    const int l15 = lane & 15;
    const int kgl = lane >> 4;
    const int lq  = kgl * 4;

    const int at   = w;         // staging t = wave id
    const int arow = lane;      // staging row

    const float a2v = alphap[0];

    f32x4 acc[T_][2][4];
#pragma unroll
    for (int t = 0; t < T_; ++t)
#pragma unroll
        for (int m = 0; m < 2; ++m)
#pragma unroll
            for (int n = 0; n < 4; ++n) acc[t][m][n] = (f32x4){0.f, 0.f, 0.f, 0.f};

    const unsigned char* ap = s1 + ((size_t)at * BN_ + bn0 + arow) * H_;
    const _Float16* bl = w2s + (size_t)d0i * (64 * 8192)
                             + (size_t)kgl * 1024 + (size_t)(wc + l15) * 8;

#define FC2_ACONV_WRITE(BUF, R0, R1)                                             \
    {                                                                            \
        unsigned v_[8];                                                          \
        spikes4_to_f16(R0.x, v_[0], v_[1]); spikes4_to_f16(R0.y, v_[2], v_[3]);  \
        spikes4_to_f16(R0.z, v_[4], v_[5]); spikes4_to_f16(R0.w, v_[6], v_[7]);  \
        *(uint4*)&A2[BUF][at][0][arow][0] = *(const uint4*)&v_[0];               \
        *(uint4*)&A2[BUF][at][1][arow][0] = *(const uint4*)&v_[4];               \
        spikes4_to_f16(R1.x, v_[0], v_[1]); spikes4_to_f16(R1.y, v_[2], v_[3]);  \
        spikes4_to_f16(R1.z, v_[4], v_[5]); spikes4_to_f16(R1.w, v_[6], v_[7]);  \
        *(uint4*)&A2[BUF][at][2][arow][0] = *(const uint4*)&v_[0];               \
        *(uint4*)&A2[BUF][at][3][arow][0] = *(const uint4*)&v_[4];               \
    }

#define FC2_BLOAD(KB, B0, B1)                                                    \
    {                                                                            \
        const _Float16* bp_ = bl + (size_t)(KB) * 8192;                          \
        _Pragma("unroll")                                                        \
        for (int n_ = 0; n_ < 4; ++n_) {                                         \
            B0[n_] = *(const f16x8*)(bp_ + n_ * 128);                            \
            B1[n_] = *(const f16x8*)(bp_ + 4096 + n_ * 128);                     \
        }                                                                        \
    }

    f16x8 bc0[4], bc1[4], bpA0[4], bpA1[4];

    // ---- prologue: stage kb=0 (A -> LDS buf0, B -> current reg set)
    {
        const uint4 r0 = *(const uint4*)(ap);
        const uint4 r1 = *(const uint4*)(ap + 16);
        FC2_ACONV_WRITE(0, r0, r1)
        FC2_BLOAD(0, bc0, bc1)
    }
    __syncthreads();

    int cur = 0;
    for (int kb = 0; kb < 64; ++kb) {
        uint4 r0, r1;
        if (kb < 63) {   // prefetch next A (regs) + next B (reg set)
            r0 = *(const uint4*)(ap + (kb + 1) * 32);
            r1 = *(const uint4*)(ap + (kb + 1) * 32 + 16);
            FC2_BLOAD(kb + 1, bpA0, bpA1)
        }

        // ---- compute on buf cur: 64 MFMA/wave
        __builtin_amdgcn_s_setprio(1);
#pragma unroll
        for (int t = 0; t < T_; ++t)
#pragma unroll
            for (int m = 0; m < 2; ++m) {
                const f16x8 af = *(const f16x8*)&A2[cur][t][kgl][wr + m * 16 + l15][0];
#pragma unroll
                for (int n = 0; n < 4; ++n) {
                    acc[t][m][n] = __builtin_amdgcn_mfma_f32_16x16x32_f16(af, bc0[n], acc[t][m][n], 0, 0, 0);
                    acc[t][m][n] = __builtin_amdgcn_mfma_f32_16x16x32_f16(af, bc1[n], acc[t][m][n], 0, 0, 0);
                }
            }
        __builtin_amdgcn_s_setprio(0);

        if (kb < 63) {   // write-late A staging into other buffer
            FC2_ACONV_WRITE(cur ^ 1, r0, r1)
        }
        __syncthreads();
        if (kb < 63) {
#pragma unroll
            for (int n = 0; n < 4; ++n) { bc0[n] = bpA0[n]; bc1[n] = bpA1[n]; }
        }
        cur ^= 1;
    }

    // ---- PLIF scan over t, write f32 spikes
#pragma unroll
    for (int m = 0; m < 2; ++m)
#pragma unroll
        for (int n = 0; n < 4; ++n)
#pragma unroll
            for (int q = 0; q < 4; ++q) {
                float v = 0.f;
#pragma unroll
                for (int t = 0; t < T_; ++t) {
                    v = v + a2v * (acc[t][m][n][q] - v);
                    const bool sp = (v >= 1.0f);
                    out[((size_t)t * BN_ + bn0 + wr + m * 16 + lq + q) * D_ +
                        (d0 + wc + n * 16 + l15)] = sp ? 1.0f : 0.0f;
                    if (sp) v = 0.f;
                }
            }
}

// ---------------------------------------------------------------------------
// fc2 fallback (in-kernel W2 split; layout-independent of xs/w2s).
// ---------------------------------------------------------------------------
__global__ __launch_bounds__(256, 2)
void k_fc2(const unsigned char* __restrict__ s1, const float* __restrict__ W2,
           const float* __restrict__ alphap, float* __restrict__ out)
{
    __shared__ _Float16 A2[2][4][4][64][8];     // [buf][t][kg][row][k8]   32KB
    __shared__ _Float16 B2[2][2][4][128][8];    // [buf][sp][kg][col][k8]  32KB

    const int tid  = threadIdx.x;
    const int lane = tid & 63;
    const int w    = tid >> 6;
    const int wr   = (w >> 1) * 32;
    const int wc   = (w & 1) * 64;
    const int bn0  = blockIdx.x * 64;
    const int d0   = blockIdx.y * 128;

    const int l15 = lane & 15;
    const int kgl = lane >> 4;
    const int lq  = kgl * 4;

    const int bcol = tid & 127;
    const int bkh  = tid >> 7;
    const int at   = tid >> 6;
    const int arow = lane;

    const float a2v = alphap[0];

    f32x4 acc[T_][2][4];
#pragma unroll
    for (int t = 0; t < T_; ++t)
#pragma unroll
        for (int m = 0; m < 2; ++m)
#pragma unroll
            for (int n = 0; n < 4; ++n) acc[t][m][n] = (f32x4){0.f, 0.f, 0.f, 0.f};

    const unsigned char* ap = s1 + ((size_t)at * BN_ + bn0 + arow) * H_;
    const float*         wp0 = W2 + (size_t)(d0 + bcol) * H_ + bkh * 16;

    {
        const uint4 r0 = *(const uint4*)(ap);
        const uint4 r1 = *(const uint4*)(ap + 16);
        unsigned v[8];
        spikes4_to_f16(r0.x, v[0], v[1]); spikes4_to_f16(r0.y, v[2], v[3]);
        spikes4_to_f16(r0.z, v[4], v[5]); spikes4_to_f16(r0.w, v[6], v[7]);
        *(uint4*)&A2[0][at][0][arow][0] = *(const uint4*)&v[0];
        *(uint4*)&A2[0][at][1][arow][0] = *(const uint4*)&v[4];
        spikes4_to_f16(r1.x, v[0], v[1]); spikes4_to_f16(r1.y, v[2], v[3]);
        spikes4_to_f16(r1.z, v[4], v[5]); spikes4_to_f16(r1.w, v[6], v[7]);
        *(uint4*)&A2[0][at][2][arow][0] = *(const uint4*)&v[0];
        *(uint4*)&A2[0][at][3][arow][0] = *(const uint4*)&v[4];

        const f4 w0 = *(const f4*)wp0, w1 = *(const f4*)(wp0 + 4);
        const f4 w2 = *(const f4*)(wp0 + 8), w3 = *(const f4*)(wp0 + 12);
        f16x8 hA, lA, hB, lB;
        split8(w0, w1, hA, lA); split8(w2, w3, hB, lB);
        *(f16x8*)&B2[0][0][2 * bkh][bcol][0]     = hA;
        *(f16x8*)&B2[0][0][2 * bkh + 1][bcol][0] = hB;
        *(f16x8*)&B2[0][1][2 * bkh][bcol][0]     = lA;
        *(f16x8*)&B2[0][1][2 * bkh + 1][bcol][0] = lB;
    }
    __syncthreads();

    int cur = 0;
    for (int kb = 0; kb < 64; ++kb) {
        uint4 r0, r1; f4 w0, w1, w2, w3;
        if (kb < 63) {
            r0 = *(const uint4*)(ap + (kb + 1) * 32);
            r1 = *(const uint4*)(ap + (kb + 1) * 32 + 16);
            const float* wp = wp0 + (kb + 1) * 32;
            w0 = *(const f4*)wp;       w1 = *(const f4*)(wp + 4);
            w2 = *(const f4*)(wp + 8); w3 = *(const f4*)(wp + 12);
        }

        f16x8 bf0[4], bf1[4];
#pragma unroll
        for (int n = 0; n < 4; ++n) {
            bf0[n] = *(const f16x8*)&B2[cur][0][kgl][wc + n * 16 + l15][0];
            bf1[n] = *(const f16x8*)&B2[cur][1][kgl][wc + n * 16 + l15][0];
        }
#pragma unroll
        for (int t = 0; t < T_; ++t)
#pragma unroll
            for (int m = 0; m < 2; ++m) {
                const f16x8 af = *(const f16x8*)&A2[cur][t][kgl][wr + m * 16 + l15][0];
#pragma unroll
                for (int n = 0; n < 4; ++n) {
                    acc[t][m][n] = __builtin_amdgcn_mfma_f32_16x16x32_f16(af, bf0[n], acc[t][m][n], 0, 0, 0);
                    acc[t][m][n] = __builtin_amdgcn_mfma_f32_16x16x32_f16(af, bf1[n], acc[t][m][n], 0, 0, 0);
                }
            }

        if (kb < 63) {
            unsigned v[8];
            spikes4_to_f16(r0.x, v[0], v[1]); spikes4_to_f16(r0.y, v[2], v[3]);
            spikes4_to_f16(r0.z, v[4], v[5]); spikes4_to_f16(r0.w, v[6], v[7]);
            *(uint4*)&A2[cur ^ 1][at][0][arow][0] = *(const uint4*)&v[0];
            *(uint4*)&A2[cur ^ 1][at][1][arow][0] = *(const uint4*)&v[4];
            spikes4_to_f16(r1.x, v[0], v[1]); spikes4_to_f16(r1.y, v[2], v[3]);
            spikes4_to_f16(r1.z, v[4], v[5]); spikes4_to_f16(r1.w, v[6], v[7]);
            *(uint4*)&A2[cur ^ 1][at][2][arow][0] = *(const uint4*)&v[0];
            *(uint4*)&A2[cur ^ 1][at][3][arow][0] = *(const uint4*)&v[4];

            f16x8 hA, lA, hB, lB;
            split8(w0, w1, hA, lA); split8(w2, w3, hB, lB);
            *(f16x8*)&B2[cur ^ 1][0][2 * bkh][bcol][0]     = hA;
            *(f16x8*)&B2[cur ^ 1][0][2 * bkh + 1][bcol][0] = hB;
            *(f16x8*)&B2[cur ^ 1][1][2 * bkh][bcol][0]     = lA;
            *(f16x8*)&B2[cur ^ 1][1][2 * bkh + 1][bcol][0] = lB;
        }
        __syncthreads();
        cur ^= 1;
    }

#pragma unroll
    for (int m = 0; m < 2; ++m)
#pragma unroll
        for (int n = 0; n < 4; ++n)
#pragma unroll
            for (int q = 0; q < 4; ++q) {
                float v = 0.f;
#pragma unroll
                for (int t = 0; t < T_; ++t) {
                    v = v + a2v * (acc[t][m][n][q] - v);
                    const bool sp = (v >= 1.0f);
                    out[((size_t)t * BN_ + bn0 + wr + m * 16 + lq + q) * D_ +
                        (d0 + wc + n * 16 + l15)] = sp ? 1.0f : 0.0f;
                    if (sp) v = 0.f;
                }
            }
}

extern "C" void kernel_launch(void* const* d_in, const int* in_sizes, int n_in,
                              void* d_out, int out_size, void* d_ws, size_t ws_size,
                              hipStream_t stream) {
    const float* x      = (const float*)d_in[0];
    const float* W1     = (const float*)d_in[1];
    const float* W2     = (const float*)d_in[2];
    const float* alpha1 = (const float*)d_in[3];
    const float* alpha2 = (const float*)d_in[4];
    float* out = (float*)d_out;

    unsigned char* s1 = (unsigned char*)d_ws;       // [T][BN][H] u8 = 64 MiB
    _Float16* xs = (_Float16*)d_out;                // x hi/lo split scratch (64 MiB),
                                                    // fully overwritten by k_fc2* at the end
    const size_t S1_BYTES  = (size_t)T_ * BN_ * H_;                     // 64 MiB
    const size_t W1S_BYTES = (size_t)H_ * D_ * 2 * sizeof(_Float16);    // 4 MiB
    const size_t W2S_BYTES = (size_t)D_ * H_ * 2 * sizeof(_Float16);    // 4 MiB

    k_split<<<dim3(8192), dim3(256), 0, stream>>>(x, xs);

    _Float16* w1s = (_Float16*)((char*)d_ws + S1_BYTES);
    k_splitW<<<dim3(512), dim3(256), 0, stream>>>(W1, w1s);
    k_fc1d<<<dim3(4096), dim3(256), 0, stream>>>(xs, w1s, alpha1, s1);

    if (ws_size >= S1_BYTES + W1S_BYTES + W2S_BYTES) {
        _Float16* w2s = (_Float16*)((char*)d_ws + S1_BYTES + W1S_BYTES);
        k_splitW2<<<dim3(512), dim3(256), 0, stream>>>(W2, w2s);
        k_fc2b<<<dim3(128, 4), dim3(256), 0, stream>>>(s1, w2s, alpha2, out);
    } else {
        k_fc2<<<dim3(128, 4), dim3(256), 0, stream>>>(s1, W2, alpha2, out);
    }
}

// Round 17
// 281.793 us; speedup vs baseline: 1.5603x; 1.5603x over previous
//
#include <hip/hip_runtime.h>

#define T_  4
#define BN_ 8192
#define D_  512
#define H_  2048

typedef float f4 __attribute__((ext_vector_type(4)));
typedef float f32x4 __attribute__((ext_vector_type(4)));
typedef _Float16 f16x8 __attribute__((ext_vector_type(8)));

// hi = RN_f16(v), lo = RN_f16(v - hi); v - (float)hi is exact (Sterbenz).
__device__ __forceinline__ void split8(const f4 u0, const f4 u1, f16x8& hi, f16x8& lo) {
#pragma unroll
    for (int i = 0; i < 4; ++i) {
        _Float16 a = (_Float16)u0[i]; hi[i]     = a; lo[i]     = (_Float16)(u0[i] - (float)a);
        _Float16 b = (_Float16)u1[i]; hi[4 + i] = b; lo[4 + i] = (_Float16)(u1[i] - (float)b);
    }
}

// 4 spike bytes (0/1) -> 4 packed f16 in two u32 (exact).
__device__ __forceinline__ void spikes4_to_f16(unsigned b, unsigned& lo, unsigned& hi) {
    const unsigned p0 = (b & 0xFFu) | ((b & 0xFF00u) << 8);
    const unsigned p1 = ((b >> 16) & 0xFFu) | ((b >> 8) & 0xFF0000u);
    lo = p0 * 0x3C00u;
    hi = p1 * 0x3C00u;
}

// async global->LDS, 16B per lane. lds base must be wave-uniform (HW adds lane*16).
__device__ __forceinline__ void glds16(const void* g, void* l) {
    __builtin_amdgcn_global_load_lds((const __attribute__((address_space(1))) unsigned int*)g,
                                     (__attribute__((address_space(3))) unsigned int*)l, 16, 0, 0);
}

// ---------------------------------------------------------------------------
// k_split: x fp32 [t][bn][k] -> xs (d_out scratch), 16KB chunk per (bnB32,kb):
// [t4][sp2][kg4][row32][k8] f16 (matches fc1's LDS image exactly).
// ---------------------------------------------------------------------------
__global__ __launch_bounds__(256)
void k_split(const float* __restrict__ x, _Float16* __restrict__ xs)
{
    const int b     = blockIdx.x;         // 8192 blocks
    const int t     = b & 3;
    const int k0B   = (b >> 2) & 15;
    const int bnB64 = b >> 6;
    const int kg    = threadIdx.x & 3;
    const int row64 = threadIdx.x >> 2;

    const float* src = x + ((size_t)t * BN_ + bnB64 * 64 + row64) * D_ + k0B * 32 + kg * 8;
    const f4 u0 = *(const f4*)src;
    const f4 u1 = *(const f4*)(src + 4);
    f16x8 hi, lo;
    split8(u0, u1, hi, lo);

    const int bnB32 = bnB64 * 2 + (row64 >> 5);
    const int r     = row64 & 31;
    const size_t base = (size_t)(bnB32 * 16 + k0B) * 8192 + t * 2048;
    *(f16x8*)&xs[base +        kg * 256 + r * 8] = hi;   // sp0
    *(f16x8*)&xs[base + 1024 + kg * 256 + r * 8] = lo;   // sp1
}

// ---------------------------------------------------------------------------
// k_splitW: W1 fp32 [h][k] -> w1s f16 fragment image:
// per (h0b,kb) a 16KB chunk = [sp2][kg4][col128][k8].
// ---------------------------------------------------------------------------
__global__ __launch_bounds__(256)
void k_splitW(const float* __restrict__ W1, _Float16* __restrict__ w1s)
{
    const int gid = blockIdx.x * 256 + threadIdx.x;   // 131072 total
    const int col = gid & 127;
    const int kg  = (gid >> 7) & 3;
    const int kb  = (gid >> 9) & 15;
    const int h0b = gid >> 13;                         // 0..15

    const float* src = W1 + (size_t)(h0b * 128 + col) * D_ + kb * 32 + kg * 8;
    const f4 u0 = *(const f4*)src;
    const f4 u1 = *(const f4*)(src + 4);
    f16x8 hi, lo;
    split8(u0, u1, hi, lo);

    const size_t base = (size_t)(h0b * 16 + kb) * 8192;
    *(f16x8*)&w1s[base +        kg * 1024 + col * 8] = hi;   // sp0
    *(f16x8*)&w1s[base + 4096 + kg * 1024 + col * 8] = lo;   // sp1
}

// ---------------------------------------------------------------------------
// k_splitW2: W2 fp32 [d][h] -> w2s f16 fragment image:
// per (d0b 0..3, kb 0..63) a 16KB chunk = [sp2][kg4][col128][k8].
// ---------------------------------------------------------------------------
__global__ __launch_bounds__(256)
void k_splitW2(const float* __restrict__ W2, _Float16* __restrict__ w2s)
{
    const int gid = blockIdx.x * 256 + threadIdx.x;   // 131072 total
    const int col = gid & 127;
    const int kg  = (gid >> 7) & 3;
    const int kb  = (gid >> 9) & 63;
    const int d0b = gid >> 15;                         // 0..3

    const float* src = W2 + (size_t)(d0b * 128 + col) * H_ + kb * 32 + kg * 8;
    const f4 u0 = *(const f4*)src;
    const f4 u1 = *(const f4*)(src + 4);
    f16x8 hi, lo;
    split8(u0, u1, hi, lo);

    const size_t base = (size_t)(d0b * 64 + kb) * 8192;
    *(f16x8*)&w2s[base +        kg * 1024 + col * 8] = hi;   // sp0
    *(f16x8*)&w2s[base + 4096 + kg * 1024 + col * 8] = lo;   // sp1
}

// ---------------------------------------------------------------------------
// fc1: h = x @ W1^T, 3-product f16 split, all 4 t fused.
// Tile 32(bn) x 128(h), 4 waves side-by-side (each 32x32), K-step 32.
// DEPTH-2 pipeline: 3-deep LDS A buffers (48KB, 3 blocks/CU) + 3 B reg sets;
// counted vmcnt(16/8/0). T5 setprio around the MFMA cluster. PLIF, u8 out.
// ---------------------------------------------------------------------------
__global__ __launch_bounds__(256, 3)
void k_fc1b(const _Float16* __restrict__ xs, const _Float16* __restrict__ w1s,
            const float* __restrict__ alphap, unsigned char* __restrict__ s1)
{
    __shared__ _Float16 Ab[3][T_][2][4][32][8];   // [buf][t][sp][kg][row][k8]  3x16KB

    const int tid  = threadIdx.x;
    const int lane = tid & 63;
    const int w    = tid >> 6;
    const int wc   = w * 32;                      // per-wave 32-col slice

    // panel swizzle: 16 panels of 256 blocks; within a panel the 16 readers of
    // one xs chunk (all h0i, fixed bnL) share gid%8 -> same XCD L2.
    const int gid   = blockIdx.x;                 // 0..4095
    const int panel = gid >> 8;
    const int h0i   = (gid >> 4) & 15;
    const int bnL   = gid & 15;
    const int bnB   = panel * 16 + bnL;           // 0..255
    const int bn0   = bnB * 32;
    const int h0    = h0i * 128;

    const int l15 = lane & 15;
    const int kgl = lane >> 4;
    const int lq  = kgl * 4;

    const float a1v = alphap[0];

    f32x4 acc[T_][2][2];
#pragma unroll
    for (int t = 0; t < T_; ++t)
#pragma unroll
        for (int m = 0; m < 2; ++m)
#pragma unroll
            for (int n = 0; n < 2; ++n) acc[t][m][n] = (f32x4){0.f, 0.f, 0.f, 0.f};

    const char* xbase = (const char*)xs + (size_t)bnB * 16 * 16384;
    const _Float16* bl = w1s + (size_t)h0i * (16 * 8192)
                             + (size_t)kgl * 1024 + (size_t)(wc + l15) * 8;

#define FC1_GLDS(BUF, KB)                                                        \
    {                                                                            \
        const char* cb_ = xbase + (size_t)(KB) * 16384;                          \
        _Float16* lA_ = &Ab[BUF][0][0][0][0][0];                                 \
        _Pragma("unroll")                                                        \
        for (int i_ = 0; i_ < 4; ++i_) {                                         \
            const int s_ = i_ * 4 + w;                                           \
            glds16(cb_ + s_ * 1024 + lane * 16, lA_ + s_ * 512);                 \
        }                                                                        \
    }

#define FC1_BLOAD(KB, B0, B1)                                                    \
    {                                                                            \
        const _Float16* bp_ = bl + (size_t)(KB) * 8192;                          \
        B0[0] = *(const f16x8*)(bp_);                                            \
        B0[1] = *(const f16x8*)(bp_ + 128);                                      \
        B1[0] = *(const f16x8*)(bp_ + 4096);                                     \
        B1[1] = *(const f16x8*)(bp_ + 4096 + 128);                               \
    }

#define FC1_COMPUTE(BUF, B0, B1)                                                 \
    __builtin_amdgcn_s_setprio(1);                                               \
    _Pragma("unroll")                                                            \
    for (int t_ = 0; t_ < T_; ++t_)                                              \
        _Pragma("unroll")                                                        \
        for (int m_ = 0; m_ < 2; ++m_) {                                         \
            const f16x8 a0_ = *(const f16x8*)&Ab[BUF][t_][0][kgl][m_ * 16 + l15][0]; \
            const f16x8 a1_ = *(const f16x8*)&Ab[BUF][t_][1][kgl][m_ * 16 + l15][0]; \
            _Pragma("unroll")                                                    \
            for (int n_ = 0; n_ < 2; ++n_) {                                     \
                acc[t_][m_][n_] = __builtin_amdgcn_mfma_f32_16x16x32_f16(a0_, B0[n_], acc[t_][m_][n_], 0, 0, 0); \
                acc[t_][m_][n_] = __builtin_amdgcn_mfma_f32_16x16x32_f16(a0_, B1[n_], acc[t_][m_][n_], 0, 0, 0); \
                acc[t_][m_][n_] = __builtin_amdgcn_mfma_f32_16x16x32_f16(a1_, B0[n_], acc[t_][m_][n_], 0, 0, 0); \
            }                                                                    \
        }                                                                        \
    __builtin_amdgcn_s_setprio(0);

#define FC1_SB __builtin_amdgcn_sched_barrier(0);
#define FC1_WAIT(N) asm volatile("s_waitcnt vmcnt(" #N ")" ::: "memory");

// One pipeline phase: barrier; (optionally) issue tile P+2 (B->regs, A->LDS);
// counted wait retiring exactly tile P; compute tile P.
#define FC1_PHASE(P, SC0, SC1, SP0, SP1, BUFC, BUFP, PRE, WN)                    \
    __builtin_amdgcn_s_barrier();                                                \
    FC1_SB                                                                       \
    if (PRE) {                                                                   \
        FC1_BLOAD((P) + 2, SP0, SP1)                                             \
        FC1_SB                                                                   \
        FC1_GLDS(BUFP, (P) + 2)                                                  \
        FC1_SB                                                                   \
    }                                                                            \
    FC1_WAIT(WN)                                                                 \
    FC1_SB                                                                       \
    FC1_COMPUTE(BUFC, SC0, SC1)

    f16x8 b0A[2], b0B[2], b1A[2], b1B[2], b2A[2], b2B[2];

    // prologue: issue tiles 0 and 1 in order (counted by the phase waits)
    FC1_BLOAD(0, b0A, b0B)
    FC1_SB
    FC1_GLDS(0, 0)
    FC1_SB
    FC1_BLOAD(1, b1A, b1B)
    FC1_SB
    FC1_GLDS(1, 1)
    FC1_SB

#pragma unroll 1
    for (int i = 0; i < 4; ++i) {
        const int p = 3 * i;
        FC1_PHASE(p,     b0A, b0B, b2A, b2B, 0, 2, 1, 16)
        FC1_PHASE(p + 1, b1A, b1B, b0A, b0B, 1, 0, 1, 16)
        FC1_PHASE(p + 2, b2A, b2B, b1A, b1B, 2, 1, 1, 16)
    }
    FC1_PHASE(12, b0A, b0B, b2A, b2B, 0, 2, 1, 16)   // prefetch tile 14 -> set2/buf2
    FC1_PHASE(13, b1A, b1B, b0A, b0B, 1, 0, 1, 16)   // prefetch tile 15 -> set0/buf0
    FC1_PHASE(14, b2A, b2B, b0A, b0B, 2, 0, 0, 8)    // tile 15 still in flight
    FC1_PHASE(15, b0A, b0B, b0A, b0B, 0, 0, 0, 0)

    // ---- PLIF scan over t, write u8 spikes
#pragma unroll
    for (int m = 0; m < 2; ++m)
#pragma unroll
        for (int n = 0; n < 2; ++n)
#pragma unroll
            for (int q = 0; q < 4; ++q) {
                float v = 0.f;
#pragma unroll
                for (int t = 0; t < T_; ++t) {
                    v = v + a1v * (acc[t][m][n][q] - v);
                    const bool sp = (v >= 1.0f);
                    s1[((size_t)t * BN_ + bn0 + m * 16 + lq + q) * H_ +
                       (h0 + wc + n * 16 + l15)] = sp ? (unsigned char)1 : (unsigned char)0;
                    if (sp) v = 0.f;
                }
            }
}

// ---------------------------------------------------------------------------
// fc2b: y = s1 @ W2^T, all 4 t fused. A = binary spikes (exact f16) staged in
// LDS (dbuf 2x16KB); B = pre-split w2s loaded DIRECT to ping-pong registers.
// Tile 64(bn) x 128(d), 4 waves. T5 setprio around MFMA. PLIF, f32 out.
// ---------------------------------------------------------------------------
__global__ __launch_bounds__(256, 2)
void k_fc2b(const unsigned char* __restrict__ s1, const _Float16* __restrict__ w2s,
            const float* __restrict__ alphap, float* __restrict__ out)
{
    __shared__ _Float16 A2[2][T_][4][64][8];     // [buf][t][kg][row][k8]  32KB

    const int tid  = threadIdx.x;
    const int lane = tid & 63;
    const int w    = tid >> 6;
    const int wr   = (w >> 1) * 32;
    const int wc   = (w & 1) * 64;
    const int bn0  = blockIdx.x * 64;
    const int d0i  = blockIdx.y;
    const int d0   = d0i * 128;

    const int l15 = lane & 15;
    const int kgl = lane >> 4;
    const int lq  = kgl * 4;

    const int at   = w;         // staging t = wave id
    const int arow = lane;      // staging row

    const float a2v = alphap[0];

    f32x4 acc[T_][2][4];
#pragma unroll
    for (int t = 0; t < T_; ++t)
#pragma unroll
        for (int m = 0; m < 2; ++m)
#pragma unroll
            for (int n = 0; n < 4; ++n) acc[t][m][n] = (f32x4){0.f, 0.f, 0.f, 0.f};

    const unsigned char* ap = s1 + ((size_t)at * BN_ + bn0 + arow) * H_;
    const _Float16* bl = w2s + (size_t)d0i * (64 * 8192)
                             + (size_t)kgl * 1024 + (size_t)(wc + l15) * 8;

#define FC2_ACONV_WRITE(BUF, R0, R1)                                             \
    {                                                                            \
        unsigned v_[8];                                                          \
        spikes4_to_f16(R0.x, v_[0], v_[1]); spikes4_to_f16(R0.y, v_[2], v_[3]);  \
        spikes4_to_f16(R0.z, v_[4], v_[5]); spikes4_to_f16(R0.w, v_[6], v_[7]);  \
        *(uint4*)&A2[BUF][at][0][arow][0] = *(const uint4*)&v_[0];               \
        *(uint4*)&A2[BUF][at][1][arow][0] = *(const uint4*)&v_[4];               \
        spikes4_to_f16(R1.x, v_[0], v_[1]); spikes4_to_f16(R1.y, v_[2], v_[3]);  \
        spikes4_to_f16(R1.z, v_[4], v_[5]); spikes4_to_f16(R1.w, v_[6], v_[7]);  \
        *(uint4*)&A2[BUF][at][2][arow][0] = *(const uint4*)&v_[0];               \
        *(uint4*)&A2[BUF][at][3][arow][0] = *(const uint4*)&v_[4];               \
    }

#define FC2_BLOAD(KB, B0, B1)                                                    \
    {                                                                            \
        const _Float16* bp_ = bl + (size_t)(KB) * 8192;                          \
        _Pragma("unroll")                                                        \
        for (int n_ = 0; n_ < 4; ++n_) {                                         \
            B0[n_] = *(const f16x8*)(bp_ + n_ * 128);                            \
            B1[n_] = *(const f16x8*)(bp_ + 4096 + n_ * 128);                     \
        }                                                                        \
    }

    f16x8 bc0[4], bc1[4], bpA0[4], bpA1[4];

    // ---- prologue: stage kb=0 (A -> LDS buf0, B -> current reg set)
    {
        const uint4 r0 = *(const uint4*)(ap);
        const uint4 r1 = *(const uint4*)(ap + 16);
        FC2_ACONV_WRITE(0, r0, r1)
        FC2_BLOAD(0, bc0, bc1)
    }
    __syncthreads();

    int cur = 0;
    for (int kb = 0; kb < 64; ++kb) {
        uint4 r0, r1;
        if (kb < 63) {   // prefetch next A (regs) + next B (reg set)
            r0 = *(const uint4*)(ap + (kb + 1) * 32);
            r1 = *(const uint4*)(ap + (kb + 1) * 32 + 16);
            FC2_BLOAD(kb + 1, bpA0, bpA1)
        }

        // ---- compute on buf cur: 64 MFMA/wave
        __builtin_amdgcn_s_setprio(1);
#pragma unroll
        for (int t = 0; t < T_; ++t)
#pragma unroll
            for (int m = 0; m < 2; ++m) {
                const f16x8 af = *(const f16x8*)&A2[cur][t][kgl][wr + m * 16 + l15][0];
#pragma unroll
                for (int n = 0; n < 4; ++n) {
                    acc[t][m][n] = __builtin_amdgcn_mfma_f32_16x16x32_f16(af, bc0[n], acc[t][m][n], 0, 0, 0);
                    acc[t][m][n] = __builtin_amdgcn_mfma_f32_16x16x32_f16(af, bc1[n], acc[t][m][n], 0, 0, 0);
                }
            }
        __builtin_amdgcn_s_setprio(0);

        if (kb < 63) {   // write-late A staging into other buffer
            FC2_ACONV_WRITE(cur ^ 1, r0, r1)
        }
        __syncthreads();
        if (kb < 63) {
#pragma unroll
            for (int n = 0; n < 4; ++n) { bc0[n] = bpA0[n]; bc1[n] = bpA1[n]; }
        }
        cur ^= 1;
    }

    // ---- PLIF scan over t, write f32 spikes
#pragma unroll
    for (int m = 0; m < 2; ++m)
#pragma unroll
        for (int n = 0; n < 4; ++n)
#pragma unroll
            for (int q = 0; q < 4; ++q) {
                float v = 0.f;
#pragma unroll
                for (int t = 0; t < T_; ++t) {
                    v = v + a2v * (acc[t][m][n][q] - v);
                    const bool sp = (v >= 1.0f);
                    out[((size_t)t * BN_ + bn0 + wr + m * 16 + lq + q) * D_ +
                        (d0 + wc + n * 16 + l15)] = sp ? 1.0f : 0.0f;
                    if (sp) v = 0.f;
                }
            }
}

// ---------------------------------------------------------------------------
// fc2 fallback (in-kernel W2 split; layout-independent of xs/w2s).
// ---------------------------------------------------------------------------
__global__ __launch_bounds__(256, 2)
void k_fc2(const unsigned char* __restrict__ s1, const float* __restrict__ W2,
           const float* __restrict__ alphap, float* __restrict__ out)
{
    __shared__ _Float16 A2[2][4][4][64][8];     // [buf][t][kg][row][k8]   32KB
    __shared__ _Float16 B2[2][2][4][128][8];    // [buf][sp][kg][col][k8]  32KB

    const int tid  = threadIdx.x;
    const int lane = tid & 63;
    const int w    = tid >> 6;
    const int wr   = (w >> 1) * 32;
    const int wc   = (w & 1) * 64;
    const int bn0  = blockIdx.x * 64;
    const int d0   = blockIdx.y * 128;

    const int l15 = lane & 15;
    const int kgl = lane >> 4;
    const int lq  = kgl * 4;

    const int bcol = tid & 127;
    const int bkh  = tid >> 7;
    const int at   = tid >> 6;
    const int arow = lane;

    const float a2v = alphap[0];

    f32x4 acc[T_][2][4];
#pragma unroll
    for (int t = 0; t < T_; ++t)
#pragma unroll
        for (int m = 0; m < 2; ++m)
#pragma unroll
            for (int n = 0; n < 4; ++n) acc[t][m][n] = (f32x4){0.f, 0.f, 0.f, 0.f};

    const unsigned char* ap = s1 + ((size_t)at * BN_ + bn0 + arow) * H_;
    const float*         wp0 = W2 + (size_t)(d0 + bcol) * H_ + bkh * 16;

    {
        const uint4 r0 = *(const uint4*)(ap);
        const uint4 r1 = *(const uint4*)(ap + 16);
        unsigned v[8];
        spikes4_to_f16(r0.x, v[0], v[1]); spikes4_to_f16(r0.y, v[2], v[3]);
        spikes4_to_f16(r0.z, v[4], v[5]); spikes4_to_f16(r0.w, v[6], v[7]);
        *(uint4*)&A2[0][at][0][arow][0] = *(const uint4*)&v[0];
        *(uint4*)&A2[0][at][1][arow][0] = *(const uint4*)&v[4];
        spikes4_to_f16(r1.x, v[0], v[1]); spikes4_to_f16(r1.y, v[2], v[3]);
        spikes4_to_f16(r1.z, v[4], v[5]); spikes4_to_f16(r1.w, v[6], v[7]);
        *(uint4*)&A2[0][at][2][arow][0] = *(const uint4*)&v[0];
        *(uint4*)&A2[0][at][3][arow][0] = *(const uint4*)&v[4];

        const f4 w0 = *(const f4*)wp0, w1 = *(const f4*)(wp0 + 4);
        const f4 w2 = *(const f4*)(wp0 + 8), w3 = *(const f4*)(wp0 + 12);
        f16x8 hA, lA, hB, lB;
        split8(w0, w1, hA, lA); split8(w2, w3, hB, lB);
        *(f16x8*)&B2[0][0][2 * bkh][bcol][0]     = hA;
        *(f16x8*)&B2[0][0][2 * bkh + 1][bcol][0] = hB;
        *(f16x8*)&B2[0][1][2 * bkh][bcol][0]     = lA;
        *(f16x8*)&B2[0][1][2 * bkh + 1][bcol][0] = lB;
    }
    __syncthreads();

    int cur = 0;
    for (int kb = 0; kb < 64; ++kb) {
        uint4 r0, r1; f4 w0, w1, w2, w3;
        if (kb < 63) {
            r0 = *(const uint4*)(ap + (kb + 1) * 32);
            r1 = *(const uint4*)(ap + (kb + 1) * 32 + 16);
            const float* wp = wp0 + (kb + 1) * 32;
            w0 = *(const f4*)wp;       w1 = *(const f4*)(wp + 4);
            w2 = *(const f4*)(wp + 8); w3 = *(const f4*)(wp + 12);
        }

        f16x8 bf0[4], bf1[4];
#pragma unroll
        for (int n = 0; n < 4; ++n) {
            bf0[n] = *(const f16x8*)&B2[cur][0][kgl][wc + n * 16 + l15][0];
            bf1[n] = *(const f16x8*)&B2[cur][1][kgl][wc + n * 16 + l15][0];
        }
#pragma unroll
        for (int t = 0; t < T_; ++t)
#pragma unroll
            for (int m = 0; m < 2; ++m) {
                const f16x8 af = *(const f16x8*)&A2[cur][t][kgl][wr + m * 16 + l15][0];
#pragma unroll
                for (int n = 0; n < 4; ++n) {
                    acc[t][m][n] = __builtin_amdgcn_mfma_f32_16x16x32_f16(af, bf0[n], acc[t][m][n], 0, 0, 0);
                    acc[t][m][n] = __builtin_amdgcn_mfma_f32_16x16x32_f16(af, bf1[n], acc[t][m][n], 0, 0, 0);
                }
            }

        if (kb < 63) {
            unsigned v[8];
            spikes4_to_f16(r0.x, v[0], v[1]); spikes4_to_f16(r0.y, v[2], v[3]);
            spikes4_to_f16(r0.z, v[4], v[5]); spikes4_to_f16(r0.w, v[6], v[7]);
            *(uint4*)&A2[cur ^ 1][at][0][arow][0] = *(const uint4*)&v[0];
            *(uint4*)&A2[cur ^ 1][at][1][arow][0] = *(const uint4*)&v[4];
            spikes4_to_f16(r1.x, v[0], v[1]); spikes4_to_f16(r1.y, v[2], v[3]);
            spikes4_to_f16(r1.z, v[4], v[5]); spikes4_to_f16(r1.w, v[6], v[7]);
            *(uint4*)&A2[cur ^ 1][at][2][arow][0] = *(const uint4*)&v[0];
            *(uint4*)&A2[cur ^ 1][at][3][arow][0] = *(const uint4*)&v[4];

            f16x8 hA, lA, hB, lB;
            split8(w0, w1, hA, lA); split8(w2, w3, hB, lB);
            *(f16x8*)&B2[cur ^ 1][0][2 * bkh][bcol][0]     = hA;
            *(f16x8*)&B2[cur ^ 1][0][2 * bkh + 1][bcol][0] = hB;
            *(f16x8*)&B2[cur ^ 1][1][2 * bkh][bcol][0]     = lA;
            *(f16x8*)&B2[cur ^ 1][1][2 * bkh + 1][bcol][0] = lB;
        }
        __syncthreads();
        cur ^= 1;
    }

#pragma unroll
    for (int m = 0; m < 2; ++m)
#pragma unroll
        for (int n = 0; n < 4; ++n)
#pragma unroll
            for (int q = 0; q < 4; ++q) {
                float v = 0.f;
#pragma unroll
                for (int t = 0; t < T_; ++t) {
                    v = v + a2v * (acc[t][m][n][q] - v);
                    const bool sp = (v >= 1.0f);
                    out[((size_t)t * BN_ + bn0 + wr + m * 16 + lq + q) * D_ +
                        (d0 + wc + n * 16 + l15)] = sp ? 1.0f : 0.0f;
                    if (sp) v = 0.f;
                }
            }
}

extern "C" void kernel_launch(void* const* d_in, const int* in_sizes, int n_in,
                              void* d_out, int out_size, void* d_ws, size_t ws_size,
                              hipStream_t stream) {
    const float* x      = (const float*)d_in[0];
    const float* W1     = (const float*)d_in[1];
    const float* W2     = (const float*)d_in[2];
    const float* alpha1 = (const float*)d_in[3];
    const float* alpha2 = (const float*)d_in[4];
    float* out = (float*)d_out;

    unsigned char* s1 = (unsigned char*)d_ws;       // [T][BN][H] u8 = 64 MiB
    _Float16* xs = (_Float16*)d_out;                // x hi/lo split scratch (64 MiB),
                                                    // fully overwritten by k_fc2* at the end
    const size_t S1_BYTES  = (size_t)T_ * BN_ * H_;                     // 64 MiB
    const size_t W1S_BYTES = (size_t)H_ * D_ * 2 * sizeof(_Float16);    // 4 MiB
    const size_t W2S_BYTES = (size_t)D_ * H_ * 2 * sizeof(_Float16);    // 4 MiB

    k_split<<<dim3(8192), dim3(256), 0, stream>>>(x, xs);

    _Float16* w1s = (_Float16*)((char*)d_ws + S1_BYTES);
    k_splitW<<<dim3(512), dim3(256), 0, stream>>>(W1, w1s);
    k_fc1b<<<dim3(4096), dim3(256), 0, stream>>>(xs, w1s, alpha1, s1);

    if (ws_size >= S1_BYTES + W1S_BYTES + W2S_BYTES) {
        _Float16* w2s = (_Float16*)((char*)d_ws + S1_BYTES + W1S_BYTES);
        k_splitW2<<<dim3(512), dim3(256), 0, stream>>>(W2, w2s);
        k_fc2b<<<dim3(128, 4), dim3(256), 0, stream>>>(s1, w2s, alpha2, out);
    } else {
        k_fc2<<<dim3(128, 4), dim3(256), 0, stream>>>(s1, W2, alpha2, out);
    }
}